// Round 20
// baseline (311.887 us; speedup 1.0000x reference)
//
#include <hip/hip_runtime.h>
#include <hip/hip_bf16.h>
#include <cstdint>

typedef _Float16 h8 __attribute__((ext_vector_type(8)));
typedef _Float16 h4 __attribute__((ext_vector_type(4)));
typedef float    f4 __attribute__((ext_vector_type(4)));
typedef float    fx16 __attribute__((ext_vector_type(16)));

// Dims: B=16, Cin=256, Ch=128, Br=8, H=W=64, 4096 px/image, 65536 px total.
// ws layout:
//   W1r  @ 0           4,718,592 B  (f16 [ci8][tap9][g8][128c][32ch slot-XOR])
//   W2r  @ 4718592       524,288 B  (f16 [g][kc4][256co][32ch slot-XOR])
//   sel1 @ 5242880     2,097,152 B  (f32 [b][g][4096])
//
// LDS involutions: weight tiles: 16B slot s at row r -> s ^ ((r>>1)&3).
//                  hs: h-index ^ ((px&7)<<3)  (quad = slot^(px&7), uniform).
//
// Fused kernel = conv1 (FROZEN R16 main loop) + in-LDS h + fused sel2 +
// conv2 GEMM with counted-vmcnt 2-buffer pipeline (R20 — fixes R19's arena
// overflow: hs is 32768 halves, R19 put w2b at +16384 under it).
// Tail arena (halves, all disjoint — max-index audit):
//   hs    [0..32768)     h tile: H = px*128+ch ^ ((px&7)<<3) <= 32767
//   w2b0  [32768..40960) 16KB W2 chunk
//   w2b1  [40960..49152) 16KB W2 chunk
//   SELWf [49152..53248) 2048 f32   (dead xs region)
//   WC2f  [53248..55296) 1024 f32
//   REDf  [55296..59392) 2048 f32   (arena size 61448 ✓)
// GEMM ledger (2 loads/stage): stages 0,1 pre-staged, drained by pre-GEMM
// __syncthreads. Phase T: s_barrier; issue stage(T+1)->b[(T+1)&1] (last read
// at T-1, barrier-separated); vmcnt(2) retires stage(T) (in-flight = 4 loads,
// oldest-first m135; vmcnt(0) at T=31); ds_read b[T&1]; MFMA. stage(T) had a
// full phase to land -> wait ~free.

#define GLD16(src, dst) __builtin_amdgcn_global_load_lds( \
    (const __attribute__((address_space(1))) void*)(src), \
    (__attribute__((address_space(3))) void*)(dst), 16, 0, 0)

// ---------------- prep_w: fp32 -> f16 repack, output-major ----------------
__global__ __launch_bounds__(256) void prep_w_k(const float* __restrict__ W1,
        const float* __restrict__ W2, _Float16* __restrict__ W1r,
        _Float16* __restrict__ W2r) {
    int o8 = blockIdx.x * 256 + threadIdx.x;   // one h8 output group per thread
    if (o8 < 294912) {
        int sq = o8 & 3;
        int c  = (o8 >> 2) & 127;
        int g  = (o8 >> 9) & 7;
        int tk = o8 >> 12;                 // cik*9 + tap
        int tap = tk % 9, cik = tk / 9;
        int s = sq ^ ((c >> 1) & 3);
        int ci0 = cik * 32 + s * 8;
        const float* src = W1 + ((size_t)(g * 128 + c) * 256 + ci0) * 9 + tap;
        h8 v;
        #pragma unroll
        for (int e = 0; e < 8; ++e) v[e] = (_Float16)src[e * 9];
        *(h8*)(W1r + (size_t)o8 * 8) = v;
    } else {
        int ow = o8 - 294912;              // W2r h8 groups: 32768
        int sq = ow & 3;                   // physical 16B slot
        int co = (ow >> 2) & 255;
        int kc = (ow >> 10) & 3;
        int g  = ow >> 12;
        int s = sq ^ ((co >> 1) & 3);      // logical 8-half group (involution)
        const float* src = W2 + ((size_t)(g * 256 + co) * 128) + kc * 32 + s * 8;
        h8 v;
        #pragma unroll
        for (int e = 0; e < 8; ++e) v[e] = (_Float16)src[e];
        *(h8*)(W2r + (size_t)ow * 8) = v;
    }
}

// ---------------- prep_x: sel1 softmax, 2 threads/px ----------------
__global__ __launch_bounds__(256) void prep_x_k(const float* __restrict__ x,
        const float* __restrict__ Wc1, const float* __restrict__ bc1,
        float* __restrict__ sel1) {
    __shared__ float wc[2048];            // Wc1 [8][256]
    __shared__ float red[1024];           // [128 px][8 g] partial from upper half
    int t = threadIdx.x;
    for (int i = t; i < 2048; i += 256) wc[i] = Wc1[i];
    __syncthreads();
    int pxl = t & 127, ch = t >> 7;       // ch: c-half 0/1
    int pix = blockIdx.x * 128 + pxl;
    int b = pix >> 12, p = pix & 4095;
    const float* xp = x + (size_t)b * 1048576 + (size_t)ch * 524288 + p;
    float lg[8] = {0.f,0.f,0.f,0.f,0.f,0.f,0.f,0.f};
    for (int c = 0; c < 128; ++c) {
        float v = fmaxf(xp[(size_t)c * 4096], 0.f);
        #pragma unroll
        for (int g = 0; g < 8; ++g) lg[g] += wc[g * 256 + ch * 128 + c] * v;
    }
    if (ch)
        #pragma unroll
        for (int g = 0; g < 8; ++g) red[pxl * 8 + g] = lg[g];
    __syncthreads();
    if (!ch) {
        float m = -1e30f;
        #pragma unroll
        for (int g = 0; g < 8; ++g) {
            lg[g] += red[pxl * 8 + g] + bc1[g];
            m = fmaxf(m, lg[g]);
        }
        float sum = 0.f;
        #pragma unroll
        for (int g = 0; g < 8; ++g) { lg[g] = __expf(lg[g] - m); sum += lg[g]; }
        float inv = 1.f / sum;
        #pragma unroll
        for (int g = 0; g < 8; ++g)
            sel1[(size_t)(b * 8 + g) * 4096 + p] = lg[g] * inv;
    }
}

// -------- fused conv1 (frozen R16) + sel2 + conv2 + residual --------------
__global__ __launch_bounds__(512) void conv1_k(const float* __restrict__ x,
        const _Float16* __restrict__ W1r, const _Float16* __restrict__ W2r,
        const float* __restrict__ sel1, const float* __restrict__ Wc2,
        const float* __restrict__ bc2, const float* __restrict__ b1,
        const float* __restrict__ b2, float* __restrict__ out) {
    __shared__ _Float16 arena[61448];
    _Float16* xs = arena + 49152;         // conv1 xs [6r][64c][32ch] + zero @12288
    int t = threadIdx.x;
    int b = blockIdx.y, yt = blockIdx.x;  // yt: group of 4 output rows
    int y0 = yt * 4;
    int w = t >> 6, l = t & 63;
    int wm = w >> 2, wn = w & 3;          // wm: 64-ch half, wn: output row (64px)
    int l31 = l & 31, kq2 = l >> 5;
    if (t < 8) xs[12288 + t] = (_Float16)0.f;   // zero slot

    fx16 acc[2][2];                       // [m][nf]
    #pragma unroll
    for (int m = 0; m < 2; ++m)
        #pragma unroll
        for (int n = 0; n < 2; ++n)
            #pragma unroll
            for (int e = 0; e < 16; ++e) acc[m][n][e] = 0.f;

    auto stage_w = [&](int P, int bi) {   // one 4-expert chunk (32 KB)
        const _Float16* srcw = W1r + (size_t)P * 16384 + t * 8;
        _Float16* dw = arena + bi * 16384 + t * 8;
        #pragma unroll
        for (int it = 0; it < 4; ++it)
            GLD16(srcw + it * 4096, dw + it * 4096);
    };

    // lane constants (R6-identical)
    int px[2];
    #pragma unroll
    for (int nf = 0; nf < 2; ++nf) px[nf] = wn * 64 + nf * 32 + l31;
    bool e0 = (l31 == 0), e63 = (l31 == 31);
    int afo[2][2];
    #pragma unroll
    for (int m = 0; m < 2; ++m)
        #pragma unroll
        for (int kc = 0; kc < 2; ++kc) {
            int c = wm * 64 + m * 32 + l31;
            afo[m][kc] = c * 32 + (((kc * 2 + kq2) ^ ((c >> 1) & 3)) * 8);
        }
    int ba[2][3][2];
    #pragma unroll
    for (int nf = 0; nf < 2; ++nf)
        #pragma unroll
        for (int kx = 0; kx < 3; ++kx) {
            int rz = px[nf] + kx - 1;
            #pragma unroll
            for (int kc = 0; kc < 2; ++kc)
                ba[nf][kx][kc] = rz * 32 + (((kc * 2 + kq2) ^ ((rz >> 1) & 3)) * 8);
        }
    h8 selv[2];
    #pragma unroll
    for (int nf = 0; nf < 2; ++nf)
        #pragma unroll
        for (int g = 0; g < 8; ++g)
            selv[nf][g] = (_Float16)sel1[(size_t)(b * 8 + g) * 4096 + yt * 256 + px[nf]];

    h8 bfr[2][2];                         // B-frags for current tap [nf][kc]

    stage_w(0, 0);
    stage_w(1, 1);

    #pragma unroll 1
    for (int ci = 0; ci < 8; ++ci) {
        if (t < 384) {
            int r = t >> 6, col = t & 63;
            int rc = r * 64 + col;
            int yi = y0 - 1 + r;
            _Float16* dx = xs + rc * 32;
            int rx = (rc >> 1) & 3;
            if (yi >= 0 && yi < 64) {
                const float* xp = x + ((size_t)(b * 256 + ci * 32)) * 4096 + yi * 64 + col;
                float v[32];
                #pragma unroll
                for (int c2 = 0; c2 < 32; ++c2)
                    v[c2] = fmaxf(xp[(size_t)c2 * 4096], 0.f);
                #pragma unroll
                for (int qq = 0; qq < 4; ++qq) {
                    h8 hv;
                    #pragma unroll
                    for (int e = 0; e < 8; ++e) hv[e] = (_Float16)v[qq * 8 + e];
                    *(h8*)(dx + (qq ^ rx) * 8) = hv;   // involution: read undoes it
                }
            } else {
                const h8 HZ = {};
                #pragma unroll
                for (int qq = 0; qq < 4; ++qq)
                    *(h8*)(dx + (qq ^ rx) * 8) = HZ;
            }
        }
        __syncthreads();                  // publish xs (full drain, 1x per ci)
        #pragma unroll 1
        for (int ky = 0; ky < 3; ++ky) {
            #pragma unroll
            for (int kx = 0; kx < 3; ++kx) {
                int tap = ci * 9 + ky * 3 + kx;
                #pragma unroll
                for (int nf = 0; nf < 2; ++nf)
                    #pragma unroll
                    for (int kc = 0; kc < 2; ++kc) {
                        int a = ba[nf][kx][kc] + ky * 2048;
                        if (kx == 0 && nf == 0) a = e0 ? 12288 : a;
                        if (kx == 2 && nf == 1) a = e63 ? 12288 : a;
                        bfr[nf][kc] = *(const h8*)(xs + a);
                    }
                #pragma unroll
                for (int gp = 0; gp < 2; ++gp) {
                    int P = tap * 2 + gp;
                    __builtin_amdgcn_s_barrier();      // raw barrier, no drain
                    if (P >= 143) {
                        asm volatile("s_waitcnt vmcnt(0)" ::: "memory");
                    } else {
                        asm volatile("s_waitcnt vmcnt(4)" ::: "memory");
                    }
                    __builtin_amdgcn_sched_barrier(0);
                    const _Float16* wp = arena + ((2 * kx + gp) % 3) * 16384;
                    __builtin_amdgcn_s_setprio(1);
                    #pragma unroll
                    for (int gl = 0; gl < 4; ++gl) {
                        #pragma unroll
                        for (int kc = 0; kc < 2; ++kc) {
                            h8 a0 = *(const h8*)(wp + gl * 4096 + afo[0][kc]);
                            h8 a1 = *(const h8*)(wp + gl * 4096 + afo[1][kc]);
                            #pragma unroll
                            for (int nf = 0; nf < 2; ++nf) {
                                h8 bs = bfr[nf][kc] * selv[nf][gp * 4 + gl];
                                acc[0][nf] = __builtin_amdgcn_mfma_f32_32x32x16_f16(
                                    a0, bs, acc[0][nf], 0, 0, 0);
                                acc[1][nf] = __builtin_amdgcn_mfma_f32_32x32x16_f16(
                                    a1, bs, acc[1][nf], 0, 0, 0);
                            }
                        }
                    }
                    __builtin_amdgcn_s_setprio(0);
                    if (P < 142) stage_w(P + 2, (2 * kx + gp + 2) % 3);
                }
            }
        }
    }
    // ---------------- fused tail (R20: fixed arena + counted 2-buf GEMM) ---
    __syncthreads();                      // wt + xs dead; vm/lgkm drained
    _Float16* w2b0 = arena + 32768;       // 2 x 16KB W2 chunk buffers
    _Float16* w2b1 = arena + 40960;
    float* SELWf = (float*)(arena + 49152);   // 2048 f32 [256px][8g]
    float* WC2f  = (float*)(arena + 53248);   // 1024 f32
    float* REDf  = (float*)(arena + 55296);   // 2048 f32 [256px][8g]
    // write h (bias+relu, f16) into hs = arena[0..32768), involution ^((px&7)<<3)
    // C/D (32x32): col=lane&31 -> px; row=(reg&3)+8*(reg>>2)+4*(lane>>5) -> ch
    #pragma unroll
    for (int m = 0; m < 2; ++m)
        #pragma unroll
        for (int nf = 0; nf < 2; ++nf) {
            int pxv = px[nf];
            #pragma unroll
            for (int q = 0; q < 4; ++q) {
                int c0 = wm * 64 + m * 32 + q * 8 + kq2 * 4;
                f4 bb = *(const f4*)(b1 + c0);
                h4 hv;
                #pragma unroll
                for (int r = 0; r < 4; ++r)
                    hv[r] = (_Float16)fmaxf(acc[m][nf][q * 4 + r] + bb[r], 0.f);
                int H = pxv * 128 + c0;
                *(h4*)(arena + (H ^ ((pxv & 7) << 3))) = hv;
            }
        }
    if (t < 512) { WC2f[t] = Wc2[t]; WC2f[t + 512] = Wc2[t + 512]; }
    auto stage_w2 = [&](int T, _Float16* dwb) {   // one (g,kc) chunk, 16 KB
        const _Float16* srcw = W2r + (size_t)T * 8192 + t * 8;
        _Float16* dw = dwb + t * 8;
        GLD16(srcw, dw);
        GLD16(srcw + 4096, dw + 4096);
    };
    stage_w2(0, w2b0);                    // pre-stage; drained by next sync
    stage_w2(1, w2b1);
    __syncthreads();                      // publish hs + wc2 (drains stages 0,1)
    {   // sel2 logits: 2 threads/px, 64 ch each
        int px2 = t >> 1, half = t & 1;
        float lg[8] = {0.f,0.f,0.f,0.f,0.f,0.f,0.f,0.f};
        #pragma unroll
        for (int u = 0; u < 8; ++u) {
            int H = px2 * 128 + half * 64 + u * 8;
            h8 v = *(const h8*)(arena + (H ^ ((px2 & 7) << 3)));
            #pragma unroll
            for (int e = 0; e < 8; ++e) {
                float f = (float)v[e];
                int c = half * 64 + u * 8 + e;
                #pragma unroll
                for (int g = 0; g < 8; ++g) lg[g] += WC2f[g * 128 + c] * f;
            }
        }
        if (half)
            #pragma unroll
            for (int g = 0; g < 8; ++g) REDf[px2 * 8 + g] = lg[g];
        __syncthreads();
        if (!half) {                      // softmax, one px per (even) thread
            float m2 = -1e30f;
            #pragma unroll
            for (int g = 0; g < 8; ++g) {
                lg[g] += REDf[px2 * 8 + g] + bc2[g];
                m2 = fmaxf(m2, lg[g]);
            }
            float sum = 0.f;
            #pragma unroll
            for (int g = 0; g < 8; ++g) { lg[g] = __expf(lg[g] - m2); sum += lg[g]; }
            float inv = 1.f / sum;
            #pragma unroll
            for (int g = 0; g < 8; ++g) SELWf[px2 * 8 + g] = lg[g] * inv;
        }
    }
    __syncthreads();                      // publish selw
    // GEMM: 8 waves = wm2(co-half 128) x wn4(px 64); 16x16x32; sel-scaled B
    int sl = l >> 4, l15g = l & 15;
    int pg[4];
    #pragma unroll
    for (int n = 0; n < 4; ++n) pg[n] = wn * 64 + n * 16 + l15g;
    h8 selr[4];                           // [n] element g, f16
    #pragma unroll
    for (int n = 0; n < 4; ++n)
        #pragma unroll
        for (int g = 0; g < 8; ++g)
            selr[n][g] = (_Float16)SELWf[pg[n] * 8 + g];
    int afo2[8];
    #pragma unroll
    for (int m = 0; m < 8; ++m) {
        int co = wm * 128 + m * 16 + l15g;
        afo2[m] = co * 32 + ((sl ^ ((co >> 1) & 3)) * 8);
    }
    f4 acc2[8][4];
    #pragma unroll
    for (int m = 0; m < 8; ++m)
        #pragma unroll
        for (int n = 0; n < 4; ++n) acc2[m][n] = (f4){0.f, 0.f, 0.f, 0.f};
    #pragma unroll 1
    for (int T = 0; T < 32; ++T) {        // T = g*4 + kc
        __builtin_amdgcn_s_barrier();     // phase T-1 readers done
        if (T >= 1 && T <= 30)            // stage(T+1) -> b[(T+1)&1], last read T-1
            stage_w2(T + 1, ((T + 1) & 1) ? w2b1 : w2b0);
        if (T >= 31) {
            asm volatile("s_waitcnt vmcnt(0)" ::: "memory");
        } else {                          // retire stage(T); keep stage(T+1)
            asm volatile("s_waitcnt vmcnt(2)" ::: "memory");
        }
        __builtin_amdgcn_sched_barrier(0);
        const _Float16* wp = (T & 1) ? w2b1 : w2b0;
        int kc = (T & 3) * 32;
        int g = T >> 2;
        h8 bsv[4];
        #pragma unroll
        for (int n = 0; n < 4; ++n) {
            int H = pg[n] * 128 + kc + sl * 8;
            h8 bv = *(const h8*)(arena + (H ^ ((pg[n] & 7) << 3)));
            bsv[n] = bv * selr[n][g];     // sel-scaled B
        }
        __builtin_amdgcn_s_setprio(1);
        #pragma unroll
        for (int m = 0; m < 8; ++m) {
            h8 af = *(const h8*)(wp + afo2[m]);
            #pragma unroll
            for (int n = 0; n < 4; ++n)
                acc2[m][n] = __builtin_amdgcn_mfma_f32_16x16x32_f16(
                    af, bsv[n], acc2[m][n], 0, 0, 0);
        }
        __builtin_amdgcn_s_setprio(0);
    }
    // epilogue: + b2 + residual x, fp32 NCHW out
    // 16x16 C/D: col = l15 -> px, row = sl*4 + r -> co
    #pragma unroll
    for (int m = 0; m < 8; ++m) {
        int c0 = wm * 128 + m * 16 + sl * 4;
        f4 bb = *(const f4*)(b2 + c0);
        #pragma unroll
        for (int n = 0; n < 4; ++n) {
            size_t o = (size_t)(b * 256 + c0) * 4096 + yt * 256 + pg[n];
            #pragma unroll
            for (int r = 0; r < 4; ++r)
                out[o + (size_t)r * 4096] = acc2[m][n][r] + bb[r] + x[o + (size_t)r * 4096];
        }
    }
}

extern "C" void kernel_launch(void* const* d_in, const int* in_sizes, int n_in,
                              void* d_out, int out_size, void* d_ws, size_t ws_size,
                              hipStream_t stream) {
    const float* x   = (const float*)d_in[0];
    const float* W1  = (const float*)d_in[1];
    const float* b1  = (const float*)d_in[2];
    const float* Wc1 = (const float*)d_in[3];
    const float* bc1 = (const float*)d_in[4];
    const float* W2  = (const float*)d_in[5];
    const float* b2  = (const float*)d_in[6];
    const float* Wc2 = (const float*)d_in[7];
    const float* bc2 = (const float*)d_in[8];
    float* out = (float*)d_out;
    char* ws = (char*)d_ws;
    _Float16* W1r = (_Float16*)(ws);                   //  4,718,592 B
    _Float16* W2r = (_Float16*)(ws + 4718592);         //    524,288 B
    float* sel1   = (float*)(ws + 5242880);            //  2,097,152 B

    hipLaunchKernelGGL(prep_w_k, dim3(1280), dim3(256), 0, stream, W1, W2, W1r, W2r);
    hipLaunchKernelGGL(prep_x_k, dim3(512), dim3(256), 0, stream, x, Wc1, bc1, sel1);
    hipLaunchKernelGGL(conv1_k, dim3(16, 16), dim3(512), 0, stream,
                       x, W1r, W2r, sel1, Wc2, bc2, b1, b2, out);
}

// Round 21
// 309.755 us; speedup vs baseline: 1.0069x; 1.0069x over previous
//
#include <hip/hip_runtime.h>
#include <hip/hip_bf16.h>
#include <cstdint>

typedef _Float16 h8 __attribute__((ext_vector_type(8)));
typedef _Float16 h4 __attribute__((ext_vector_type(4)));
typedef float    f4 __attribute__((ext_vector_type(4)));
typedef float    fx16 __attribute__((ext_vector_type(16)));

// Dims: B=16, Cin=256, Ch=128, Br=8, H=W=64, 4096 px/image, 65536 px total.
// ws layout:
//   W1r  @ 0           4,718,592 B  (f16 [ci8][tap9][g8][128c][32ch slot-XOR])
//   W2r  @ 4718592       524,288 B  (f16 [g][kc4][256co][32ch slot-XOR])
//   sel1 @ 5242880     2,097,152 B  (f32 [b][g][4096])
//
// LDS involutions: weight tiles: 16B slot s at row r -> s ^ ((r>>1)&3).
//                  hs: h-index ^ ((px&7)<<3)  (quad = slot^(px&7), uniform).
//
// R21 = R20 (passing, 311.9us) with prep_w + prep_x merged into one launch.
// Fused kernel = conv1 (FROZEN R16 main loop, LDS-port-saturated at 247us) +
// in-LDS h + fused sel2 + conv2 GEMM (counted-vmcnt 2-buffer) + residual out.
// Tail arena (halves, disjoint — max-index audit):
//   hs    [0..32768)  w2b0 [32768..40960)  w2b1 [40960..49152)
//   SELWf [49152..53248)  WC2f [53248..55296)  REDf [55296..59392)  (<=61448)

#define GLD16(src, dst) __builtin_amdgcn_global_load_lds( \
    (const __attribute__((address_space(1))) void*)(src), \
    (__attribute__((address_space(3))) void*)(dst), 16, 0, 0)

// ---------------- prep: weight repack (blocks 0..1279) + sel1 (1280..1791) --
__global__ __launch_bounds__(256) void prep_k(const float* __restrict__ W1,
        const float* __restrict__ W2, const float* __restrict__ x,
        const float* __restrict__ Wc1, const float* __restrict__ bc1,
        _Float16* __restrict__ W1r, _Float16* __restrict__ W2r,
        float* __restrict__ sel1) {
    int t = threadIdx.x;
    if (blockIdx.x < 1280) {
        int o8 = blockIdx.x * 256 + t;     // one h8 output group per thread
        if (o8 < 294912) {
            int sq = o8 & 3;
            int c  = (o8 >> 2) & 127;
            int g  = (o8 >> 9) & 7;
            int tk = o8 >> 12;             // cik*9 + tap
            int tap = tk % 9, cik = tk / 9;
            int s = sq ^ ((c >> 1) & 3);
            int ci0 = cik * 32 + s * 8;
            const float* src = W1 + ((size_t)(g * 128 + c) * 256 + ci0) * 9 + tap;
            h8 v;
            #pragma unroll
            for (int e = 0; e < 8; ++e) v[e] = (_Float16)src[e * 9];
            *(h8*)(W1r + (size_t)o8 * 8) = v;
        } else {
            int ow = o8 - 294912;          // W2r h8 groups: 32768
            int sq = ow & 3;               // physical 16B slot
            int co = (ow >> 2) & 255;
            int kc = (ow >> 10) & 3;
            int g  = ow >> 12;
            int s = sq ^ ((co >> 1) & 3);  // logical 8-half group (involution)
            const float* src = W2 + ((size_t)(g * 256 + co) * 128) + kc * 32 + s * 8;
            h8 v;
            #pragma unroll
            for (int e = 0; e < 8; ++e) v[e] = (_Float16)src[e];
            *(h8*)(W2r + (size_t)ow * 8) = v;
        }
        return;
    }
    // ---- sel1 softmax, 2 threads/px ----
    __shared__ float wc[2048];            // Wc1 [8][256]
    __shared__ float red[1024];           // [128 px][8 g] partial (upper half)
    for (int i = t; i < 2048; i += 256) wc[i] = Wc1[i];
    __syncthreads();
    int pxl = t & 127, ch = t >> 7;       // ch: c-half 0/1
    int pix = (blockIdx.x - 1280) * 128 + pxl;
    int b = pix >> 12, p = pix & 4095;
    const float* xp = x + (size_t)b * 1048576 + (size_t)ch * 524288 + p;
    float lg[8] = {0.f,0.f,0.f,0.f,0.f,0.f,0.f,0.f};
    for (int c = 0; c < 128; ++c) {
        float v = fmaxf(xp[(size_t)c * 4096], 0.f);
        #pragma unroll
        for (int g = 0; g < 8; ++g) lg[g] += wc[g * 256 + ch * 128 + c] * v;
    }
    if (ch)
        #pragma unroll
        for (int g = 0; g < 8; ++g) red[pxl * 8 + g] = lg[g];
    __syncthreads();
    if (!ch) {
        float m = -1e30f;
        #pragma unroll
        for (int g = 0; g < 8; ++g) {
            lg[g] += red[pxl * 8 + g] + bc1[g];
            m = fmaxf(m, lg[g]);
        }
        float sum = 0.f;
        #pragma unroll
        for (int g = 0; g < 8; ++g) { lg[g] = __expf(lg[g] - m); sum += lg[g]; }
        float inv = 1.f / sum;
        #pragma unroll
        for (int g = 0; g < 8; ++g)
            sel1[(size_t)(b * 8 + g) * 4096 + p] = lg[g] * inv;
    }
}

// -------- fused conv1 (frozen R16) + sel2 + conv2 + residual --------------
__global__ __launch_bounds__(512) void conv1_k(const float* __restrict__ x,
        const _Float16* __restrict__ W1r, const _Float16* __restrict__ W2r,
        const float* __restrict__ sel1, const float* __restrict__ Wc2,
        const float* __restrict__ bc2, const float* __restrict__ b1,
        const float* __restrict__ b2, float* __restrict__ out) {
    __shared__ _Float16 arena[61448];
    _Float16* xs = arena + 49152;         // conv1 xs [6r][64c][32ch] + zero @12288
    int t = threadIdx.x;
    int b = blockIdx.y, yt = blockIdx.x;  // yt: group of 4 output rows
    int y0 = yt * 4;
    int w = t >> 6, l = t & 63;
    int wm = w >> 2, wn = w & 3;          // wm: 64-ch half, wn: output row (64px)
    int l31 = l & 31, kq2 = l >> 5;
    if (t < 8) xs[12288 + t] = (_Float16)0.f;   // zero slot

    fx16 acc[2][2];                       // [m][nf]
    #pragma unroll
    for (int m = 0; m < 2; ++m)
        #pragma unroll
        for (int n = 0; n < 2; ++n)
            #pragma unroll
            for (int e = 0; e < 16; ++e) acc[m][n][e] = 0.f;

    auto stage_w = [&](int P, int bi) {   // one 4-expert chunk (32 KB)
        const _Float16* srcw = W1r + (size_t)P * 16384 + t * 8;
        _Float16* dw = arena + bi * 16384 + t * 8;
        #pragma unroll
        for (int it = 0; it < 4; ++it)
            GLD16(srcw + it * 4096, dw + it * 4096);
    };

    // lane constants (R6-identical)
    int px[2];
    #pragma unroll
    for (int nf = 0; nf < 2; ++nf) px[nf] = wn * 64 + nf * 32 + l31;
    bool e0 = (l31 == 0), e63 = (l31 == 31);
    int afo[2][2];
    #pragma unroll
    for (int m = 0; m < 2; ++m)
        #pragma unroll
        for (int kc = 0; kc < 2; ++kc) {
            int c = wm * 64 + m * 32 + l31;
            afo[m][kc] = c * 32 + (((kc * 2 + kq2) ^ ((c >> 1) & 3)) * 8);
        }
    int ba[2][3][2];
    #pragma unroll
    for (int nf = 0; nf < 2; ++nf)
        #pragma unroll
        for (int kx = 0; kx < 3; ++kx) {
            int rz = px[nf] + kx - 1;
            #pragma unroll
            for (int kc = 0; kc < 2; ++kc)
                ba[nf][kx][kc] = rz * 32 + (((kc * 2 + kq2) ^ ((rz >> 1) & 3)) * 8);
        }
    h8 selv[2];
    #pragma unroll
    for (int nf = 0; nf < 2; ++nf)
        #pragma unroll
        for (int g = 0; g < 8; ++g)
            selv[nf][g] = (_Float16)sel1[(size_t)(b * 8 + g) * 4096 + yt * 256 + px[nf]];

    h8 bfr[2][2];                         // B-frags for current tap [nf][kc]

    stage_w(0, 0);
    stage_w(1, 1);

    #pragma unroll 1
    for (int ci = 0; ci < 8; ++ci) {
        if (t < 384) {
            int r = t >> 6, col = t & 63;
            int rc = r * 64 + col;
            int yi = y0 - 1 + r;
            _Float16* dx = xs + rc * 32;
            int rx = (rc >> 1) & 3;
            if (yi >= 0 && yi < 64) {
                const float* xp = x + ((size_t)(b * 256 + ci * 32)) * 4096 + yi * 64 + col;
                float v[32];
                #pragma unroll
                for (int c2 = 0; c2 < 32; ++c2)
                    v[c2] = fmaxf(xp[(size_t)c2 * 4096], 0.f);
                #pragma unroll
                for (int qq = 0; qq < 4; ++qq) {
                    h8 hv;
                    #pragma unroll
                    for (int e = 0; e < 8; ++e) hv[e] = (_Float16)v[qq * 8 + e];
                    *(h8*)(dx + (qq ^ rx) * 8) = hv;   // involution: read undoes it
                }
            } else {
                const h8 HZ = {};
                #pragma unroll
                for (int qq = 0; qq < 4; ++qq)
                    *(h8*)(dx + (qq ^ rx) * 8) = HZ;
            }
        }
        __syncthreads();                  // publish xs (full drain, 1x per ci)
        #pragma unroll 1
        for (int ky = 0; ky < 3; ++ky) {
            #pragma unroll
            for (int kx = 0; kx < 3; ++kx) {
                int tap = ci * 9 + ky * 3 + kx;
                #pragma unroll
                for (int nf = 0; nf < 2; ++nf)
                    #pragma unroll
                    for (int kc = 0; kc < 2; ++kc) {
                        int a = ba[nf][kx][kc] + ky * 2048;
                        if (kx == 0 && nf == 0) a = e0 ? 12288 : a;
                        if (kx == 2 && nf == 1) a = e63 ? 12288 : a;
                        bfr[nf][kc] = *(const h8*)(xs + a);
                    }
                #pragma unroll
                for (int gp = 0; gp < 2; ++gp) {
                    int P = tap * 2 + gp;
                    __builtin_amdgcn_s_barrier();      // raw barrier, no drain
                    if (P >= 143) {
                        asm volatile("s_waitcnt vmcnt(0)" ::: "memory");
                    } else {
                        asm volatile("s_waitcnt vmcnt(4)" ::: "memory");
                    }
                    __builtin_amdgcn_sched_barrier(0);
                    const _Float16* wp = arena + ((2 * kx + gp) % 3) * 16384;
                    __builtin_amdgcn_s_setprio(1);
                    #pragma unroll
                    for (int gl = 0; gl < 4; ++gl) {
                        #pragma unroll
                        for (int kc = 0; kc < 2; ++kc) {
                            h8 a0 = *(const h8*)(wp + gl * 4096 + afo[0][kc]);
                            h8 a1 = *(const h8*)(wp + gl * 4096 + afo[1][kc]);
                            #pragma unroll
                            for (int nf = 0; nf < 2; ++nf) {
                                h8 bs = bfr[nf][kc] * selv[nf][gp * 4 + gl];
                                acc[0][nf] = __builtin_amdgcn_mfma_f32_32x32x16_f16(
                                    a0, bs, acc[0][nf], 0, 0, 0);
                                acc[1][nf] = __builtin_amdgcn_mfma_f32_32x32x16_f16(
                                    a1, bs, acc[1][nf], 0, 0, 0);
                            }
                        }
                    }
                    __builtin_amdgcn_s_setprio(0);
                    if (P < 142) stage_w(P + 2, (2 * kx + gp + 2) % 3);
                }
            }
        }
    }
    // ---------------- fused tail (R20 layout, verified) ----------------
    __syncthreads();                      // wt + xs dead; vm/lgkm drained
    _Float16* w2b0 = arena + 32768;       // 2 x 16KB W2 chunk buffers
    _Float16* w2b1 = arena + 40960;
    float* SELWf = (float*)(arena + 49152);   // 2048 f32 [256px][8g]
    float* WC2f  = (float*)(arena + 53248);   // 1024 f32
    float* REDf  = (float*)(arena + 55296);   // 2048 f32 [256px][8g]
    #pragma unroll
    for (int m = 0; m < 2; ++m)
        #pragma unroll
        for (int nf = 0; nf < 2; ++nf) {
            int pxv = px[nf];
            #pragma unroll
            for (int q = 0; q < 4; ++q) {
                int c0 = wm * 64 + m * 32 + q * 8 + kq2 * 4;
                f4 bb = *(const f4*)(b1 + c0);
                h4 hv;
                #pragma unroll
                for (int r = 0; r < 4; ++r)
                    hv[r] = (_Float16)fmaxf(acc[m][nf][q * 4 + r] + bb[r], 0.f);
                int H = pxv * 128 + c0;
                *(h4*)(arena + (H ^ ((pxv & 7) << 3))) = hv;
            }
        }
    if (t < 512) { WC2f[t] = Wc2[t]; WC2f[t + 512] = Wc2[t + 512]; }
    auto stage_w2 = [&](int T, _Float16* dwb) {   // one (g,kc) chunk, 16 KB
        const _Float16* srcw = W2r + (size_t)T * 8192 + t * 8;
        _Float16* dw = dwb + t * 8;
        GLD16(srcw, dw);
        GLD16(srcw + 4096, dw + 4096);
    };
    stage_w2(0, w2b0);                    // pre-stage; drained by next sync
    stage_w2(1, w2b1);
    __syncthreads();                      // publish hs + wc2 (drains stages 0,1)
    {   // sel2 logits: 2 threads/px, 64 ch each
        int px2 = t >> 1, half = t & 1;
        float lg[8] = {0.f,0.f,0.f,0.f,0.f,0.f,0.f,0.f};
        #pragma unroll
        for (int u = 0; u < 8; ++u) {
            int H = px2 * 128 + half * 64 + u * 8;
            h8 v = *(const h8*)(arena + (H ^ ((px2 & 7) << 3)));
            #pragma unroll
            for (int e = 0; e < 8; ++e) {
                float f = (float)v[e];
                int c = half * 64 + u * 8 + e;
                #pragma unroll
                for (int g = 0; g < 8; ++g) lg[g] += WC2f[g * 128 + c] * f;
            }
        }
        if (half)
            #pragma unroll
            for (int g = 0; g < 8; ++g) REDf[px2 * 8 + g] = lg[g];
        __syncthreads();
        if (!half) {                      // softmax, one px per (even) thread
            float m2 = -1e30f;
            #pragma unroll
            for (int g = 0; g < 8; ++g) {
                lg[g] += REDf[px2 * 8 + g] + bc2[g];
                m2 = fmaxf(m2, lg[g]);
            }
            float sum = 0.f;
            #pragma unroll
            for (int g = 0; g < 8; ++g) { lg[g] = __expf(lg[g] - m2); sum += lg[g]; }
            float inv = 1.f / sum;
            #pragma unroll
            for (int g = 0; g < 8; ++g) SELWf[px2 * 8 + g] = lg[g] * inv;
        }
    }
    __syncthreads();                      // publish selw
    // GEMM: 8 waves = wm2(co-half 128) x wn4(px 64); 16x16x32; sel-scaled B
    int sl = l >> 4, l15g = l & 15;
    int pg[4];
    #pragma unroll
    for (int n = 0; n < 4; ++n) pg[n] = wn * 64 + n * 16 + l15g;
    h8 selr[4];                           // [n] element g, f16
    #pragma unroll
    for (int n = 0; n < 4; ++n)
        #pragma unroll
        for (int g = 0; g < 8; ++g)
            selr[n][g] = (_Float16)SELWf[pg[n] * 8 + g];
    int afo2[8];
    #pragma unroll
    for (int m = 0; m < 8; ++m) {
        int co = wm * 128 + m * 16 + l15g;
        afo2[m] = co * 32 + ((sl ^ ((co >> 1) & 3)) * 8);
    }
    f4 acc2[8][4];
    #pragma unroll
    for (int m = 0; m < 8; ++m)
        #pragma unroll
        for (int n = 0; n < 4; ++n) acc2[m][n] = (f4){0.f, 0.f, 0.f, 0.f};
    #pragma unroll 1
    for (int T = 0; T < 32; ++T) {        // T = g*4 + kc
        __builtin_amdgcn_s_barrier();     // phase T-1 readers done
        if (T >= 1 && T <= 30)            // stage(T+1) -> b[(T+1)&1], last read T-1
            stage_w2(T + 1, ((T + 1) & 1) ? w2b1 : w2b0);
        if (T >= 31) {
            asm volatile("s_waitcnt vmcnt(0)" ::: "memory");
        } else {                          // retire stage(T); keep stage(T+1)
            asm volatile("s_waitcnt vmcnt(2)" ::: "memory");
        }
        __builtin_amdgcn_sched_barrier(0);
        const _Float16* wp = (T & 1) ? w2b1 : w2b0;
        int kc = (T & 3) * 32;
        int g = T >> 2;
        h8 bsv[4];
        #pragma unroll
        for (int n = 0; n < 4; ++n) {
            int H = pg[n] * 128 + kc + sl * 8;
            h8 bv = *(const h8*)(arena + (H ^ ((pg[n] & 7) << 3)));
            bsv[n] = bv * selr[n][g];     // sel-scaled B
        }
        __builtin_amdgcn_s_setprio(1);
        #pragma unroll
        for (int m = 0; m < 8; ++m) {
            h8 af = *(const h8*)(wp + afo2[m]);
            #pragma unroll
            for (int n = 0; n < 4; ++n)
                acc2[m][n] = __builtin_amdgcn_mfma_f32_16x16x32_f16(
                    af, bsv[n], acc2[m][n], 0, 0, 0);
        }
        __builtin_amdgcn_s_setprio(0);
    }
    // epilogue: + b2 + residual x, fp32 NCHW out
    #pragma unroll
    for (int m = 0; m < 8; ++m) {
        int c0 = wm * 128 + m * 16 + sl * 4;
        f4 bb = *(const f4*)(b2 + c0);
        #pragma unroll
        for (int n = 0; n < 4; ++n) {
            size_t o = (size_t)(b * 256 + c0) * 4096 + yt * 256 + pg[n];
            #pragma unroll
            for (int r = 0; r < 4; ++r)
                out[o + (size_t)r * 4096] = acc2[m][n][r] + bb[r] + x[o + (size_t)r * 4096];
        }
    }
}

extern "C" void kernel_launch(void* const* d_in, const int* in_sizes, int n_in,
                              void* d_out, int out_size, void* d_ws, size_t ws_size,
                              hipStream_t stream) {
    const float* x   = (const float*)d_in[0];
    const float* W1  = (const float*)d_in[1];
    const float* b1  = (const float*)d_in[2];
    const float* Wc1 = (const float*)d_in[3];
    const float* bc1 = (const float*)d_in[4];
    const float* W2  = (const float*)d_in[5];
    const float* b2  = (const float*)d_in[6];
    const float* Wc2 = (const float*)d_in[7];
    const float* bc2 = (const float*)d_in[8];
    float* out = (float*)d_out;
    char* ws = (char*)d_ws;
    _Float16* W1r = (_Float16*)(ws);                   //  4,718,592 B
    _Float16* W2r = (_Float16*)(ws + 4718592);         //    524,288 B
    float* sel1   = (float*)(ws + 5242880);            //  2,097,152 B

    hipLaunchKernelGGL(prep_k, dim3(1792), dim3(256), 0, stream,
                       W1, W2, x, Wc1, bc1, W1r, W2r, sel1);
    hipLaunchKernelGGL(conv1_k, dim3(16, 16), dim3(512), 0, stream,
                       x, W1r, W2r, sel1, Wc2, bc2, b1, b2, out);
}